// Round 10
// baseline (377.946 us; speedup 1.0000x reference)
//
#include <hip/hip_runtime.h>
#include <hip/hip_bf16.h>

#define NEDGE 262144
#define DIM 256
#define NNODE 50000
#define NLAYER 3
#define EPSV 1e-5f

// layer-1 fused kernel geometry: 256 blocks x 8 waves x 8 tiles x 16 rows
#define G1_BLOCKS 256
#define G1_TILES 8

// BN-layer GEMM geometry (R5-proven)
#define GBM 512
#define RC 64
#define NCH (GBM / RC)
#define GEMM_GRID (NEDGE / GBM)

typedef __attribute__((ext_vector_type(8))) short bf16x8_t;
typedef __attribute__((ext_vector_type(4))) short bf16x4_t;
typedef __attribute__((ext_vector_type(4))) float f32x4_t;

__device__ __forceinline__ float bf2f(short s) {
  unsigned u = ((unsigned)(unsigned short)s) << 16;
  return __builtin_bit_cast(float, u);
}
__device__ __forceinline__ short f2bf(float f) {
  __hip_bfloat16 h = __float2bfloat16(f);
  return __builtin_bit_cast(short, h);
}

// ---------------- Kernel 0a: convert Ws (fp32) -> bf16 (layers 2,3) ---------
extern "C" __global__ void __launch_bounds__(256)
k_cvt(const float* __restrict__ src, short* __restrict__ dst, int n) {
  int i = blockIdx.x * 256 + threadIdx.x;
  if (i < n) dst[i] = f2bf(src[i]);
}

// -------- Kernel 0b: layer-1 W' = lnw (*) W, bf16, stored as SWIZZLED image --
// Image layout: row c (512B), 16B-chunk index ch stored at position ch^(c&7).
extern "C" __global__ void __launch_bounds__(64)
k_cvtw(const float* __restrict__ W, const float* __restrict__ lnw,
       short* __restrict__ Wp) {
  const int c = blockIdx.x;
  const int j = threadIdx.x;  // handles cols j*4 .. j*4+3
  const float4 wv = *(const float4*)(W + (size_t)c * DIM + j * 4);
  const float4 lv = *(const float4*)(lnw + j * 4);
  bf16x4_t o;
  o[0] = f2bf(wv.x * lv.x); o[1] = f2bf(wv.y * lv.y);
  o[2] = f2bf(wv.z * lv.z); o[3] = f2bf(wv.w * lv.w);
  const int chunk = j >> 1;            // 16B chunk (8 bf16)
  const int half = j & 1;              // low/high 8B of the chunk
  *(bf16x4_t*)(Wp + (size_t)c * DIM + (((chunk ^ (c & 7)) << 3) + (half << 2))) = o;
}

// ---------------- Kernel 0c: convert x (fp32) -> bf16 -----------------------
extern "C" __global__ void __launch_bounds__(256)
k_cvt_x(const float* __restrict__ src, short* __restrict__ dst, int n8) {
  int i = blockIdx.x * 256 + threadIdx.x;
  if (i >= n8) return;
  const float4 a = *(const float4*)(src + (size_t)i * 8);
  const float4 b = *(const float4*)(src + (size_t)i * 8 + 4);
  bf16x8_t o;
  o[0] = f2bf(a.x); o[1] = f2bf(a.y); o[2] = f2bf(a.z); o[3] = f2bf(a.w);
  o[4] = f2bf(b.x); o[5] = f2bf(b.y); o[6] = f2bf(b.z); o[7] = f2bf(b.w);
  *(bf16x8_t*)(dst + (size_t)i * 8) = o;
}

// ======== Kernel 1: gather+LN+GEMM1, W'-in-LDS, rows-in-registers ============
// One barrier total (after W' staging). Each wave owns 8 tiles of 16 rows:
// 4 lanes/row gather the full bf16 row (s and d), LN in-register (shfl over
// the 4 kh-lanes), A-frags built on the fly, MFMA against LDS-resident W'.
// acc layout (mfma(af, wf)): D col = n*16 + (lane&15), D row = kh*4 + r.
extern "C" __global__ void __launch_bounds__(512, 2)
k_gemm1f(const short* __restrict__ xb, const int* __restrict__ ei,
         const short* __restrict__ Wp, short* __restrict__ C,
         float* __restrict__ psum, float* __restrict__ psq) {
  __shared__ short Wl[DIM * DIM];  // 128 KB swizzled W' image
  const int tid = threadIdx.x;
  const int wv = tid >> 6;
  const int lane = tid & 63;
  const int rl = lane & 15;
  const int kh = lane >> 4;

  // stage W' (linear copy of pre-swizzled image): 16 x 8KB rounds
#pragma unroll
  for (int i = 0; i < 16; ++i) {
    const short* gp = Wp + ((size_t)i * 512 + tid) * 8;
    short* lp = &Wl[((size_t)i * 512 + tid) * 8];
    __builtin_amdgcn_global_load_lds(
        (const __attribute__((address_space(1))) unsigned int*)gp,
        (__attribute__((address_space(3))) unsigned int*)lp, 16, 0, 0);
  }

  const int rowbase = blockIdx.x * (G1_TILES * 8 * 16) + wv * (G1_TILES * 16);

  f32x4_t acc[16];
  float st_s[16], st_q[16];
#pragma unroll
  for (int n = 0; n < 16; ++n) { st_s[n] = 0.f; st_q[n] = 0.f; }

  bf16x8_t sA[8], dA[8], sB[8], dB[8];
  int iAs, iAd, iBs, iBd;

  auto ldidx = [&](int t, int& is, int& id) {
    is = ei[rowbase + t * 16 + rl];
    id = ei[NEDGE + rowbase + t * 16 + rl];
  };
  auto ldgath = [&](int is, int id, bf16x8_t* s, bf16x8_t* d) {
    const short* ps = xb + (size_t)is * DIM + kh * 8;
    const short* pd = xb + (size_t)id * DIM + kh * 8;
#pragma unroll
    for (int ks = 0; ks < 8; ++ks) {
      s[ks] = *(const bf16x8_t*)(ps + ks * 32);
      d[ks] = *(const bf16x8_t*)(pd + ks * 32);
    }
  };

  auto compute = [&](int t, bf16x8_t* s, bf16x8_t* d) {
    // pass 1: row mean/var (this lane holds 64 of the row's 256 elems)
    float sum = 0.f, sq = 0.f;
#pragma unroll
    for (int ks = 0; ks < 8; ++ks)
#pragma unroll
      for (int j = 0; j < 8; ++j) {
        const float v = bf2f(s[ks][j]) + bf2f(d[ks][j]);
        sum += v;
        sq = fmaf(v, v, sq);
      }
    sum += __shfl_xor(sum, 16); sum += __shfl_xor(sum, 32);
    sq  += __shfl_xor(sq, 16);  sq  += __shfl_xor(sq, 32);
    const float mu = sum * (1.0f / DIM);
    const float inv = rsqrtf(sq * (1.0f / DIM) - mu * mu + EPSV);
    const float nmu = -mu * inv;
    // init acc
    const f32x4_t zero = {0.f, 0.f, 0.f, 0.f};
#pragma unroll
    for (int n = 0; n < 16; ++n) acc[n] = zero;
    // pass 2: per ks build af = (v)*inv - mu*inv, then 16 MFMAs vs W' frags
#pragma unroll
    for (int ks = 0; ks < 8; ++ks) {
      bf16x8_t af;
#pragma unroll
      for (int j = 0; j < 8; ++j) {
        const float v = bf2f(s[ks][j]) + bf2f(d[ks][j]);
        af[j] = f2bf(fmaf(v, inv, nmu));
      }
#pragma unroll
      for (int n = 0; n < 16; ++n) {
        const int wrow = n * 16 + rl;
        const bf16x8_t wf = *(const bf16x8_t*)(
            &Wl[wrow * DIM + (((ks * 4 + kh) ^ (wrow & 7)) << 3)]);
        acc[n] = __builtin_amdgcn_mfma_f32_16x16x32_bf16(af, wf, acc[n], 0, 0, 0);
      }
    }
    // epilogue: C (bf16, 2B stores -> 32B segments across rl lanes) + stats
    const int r0 = rowbase + t * 16 + kh * 4;
#pragma unroll
    for (int n = 0; n < 16; ++n) {
      const int col = n * 16 + rl;
      float ls = 0.f, lq = 0.f;
#pragma unroll
      for (int r = 0; r < 4; ++r) {
        const float f = acc[n][r];
        C[(size_t)(r0 + r) * DIM + col] = f2bf(f);
        ls += f;
        lq = fmaf(f, f, lq);
      }
      st_s[n] += ls;
      st_q[n] += lq;
    }
  };

  // prologue: idx 2 ahead, gathers 1 ahead
  ldidx(0, iAs, iAd);
  ldidx(1, iBs, iBd);
  ldgath(iAs, iAd, sA, dA);
  __syncthreads();  // W' resident (drains its global_load_lds)

  for (int t = 0; t < G1_TILES; t += 2) {
    if (t + 2 < G1_TILES) ldidx(t + 2, iAs, iAd);  // idxA free after gather
    if (t + 1 < G1_TILES) ldgath(iBs, iBd, sB, dB);
    compute(t, sA, dA);
    if (t + 3 < G1_TILES) ldidx(t + 3, iBs, iBd);
    if (t + 2 < G1_TILES) ldgath(iAs, iAd, sA, dA);
    if (t + 1 < G1_TILES) compute(t + 1, sB, dB);
  }

  // per-wave column stats (deterministic psum rows)
#pragma unroll
  for (int n = 0; n < 16; ++n) {
    st_s[n] += __shfl_xor(st_s[n], 16); st_s[n] += __shfl_xor(st_s[n], 32);
    st_q[n] += __shfl_xor(st_q[n], 16); st_q[n] += __shfl_xor(st_q[n], 32);
  }
  if (lane < 16) {
    const size_t prow = ((size_t)blockIdx.x * 8 + wv) * DIM;
#pragma unroll
    for (int n = 0; n < 16; ++n) {
      psum[prow + n * 16 + rl] = st_s[n];
      psq [prow + n * 16 + rl] = st_q[n];
    }
  }
}

// -------- Kernel 2: BN-layer GEMM (R5-proven): C = relu(A*sc+sh)@W^T ---------
extern "C" __global__ void __launch_bounds__(512, 2)
k_gemm_bn(const short* __restrict__ A, const short* __restrict__ W,
          short* __restrict__ C, float* __restrict__ psum, float* __restrict__ psq,
          const float* __restrict__ bsc, const float* __restrict__ bsh) {
  __shared__ short As[2][RC * DIM];
  const int tid = threadIdx.x;
  const int w = tid >> 6;
  const int lane = tid & 63;
  const int rl = lane & 15;
  const int kh = lane >> 4;
  const int row0 = blockIdx.x * GBM;
  const int colbase = w * 32;

  bf16x8_t wf[2][8];
#pragma unroll
  for (int n = 0; n < 2; ++n)
#pragma unroll
    for (int ks = 0; ks < 8; ++ks)
      wf[n][ks] = *(const bf16x8_t*)(W + (size_t)(colbase + n * 16 + rl) * DIM + ks * 32 + kh * 8);

  const int cst = tid & 31;
  float sc0[8], sh0[8];
#pragma unroll
  for (int j = 0; j < 8; ++j) {
    sc0[j] = bsc[cst * 8 + j];
    sh0[j] = bsh[cst * 8 + j];
  }

  float st_s0 = 0.f, st_s1 = 0.f, st_q0 = 0.f, st_q1 = 0.f;

  bf16x8_t ra[4], rb[4];
  auto ldregA = [&](int t) {
#pragma unroll
    for (int i = 0; i < 4; ++i) {
      const int row = (tid + i * 512) >> 5;
      ra[i] = *(const bf16x8_t*)(A + (size_t)(row0 + t * RC + row) * DIM + cst * 8);
    }
  };
  auto ldregB = [&](int t) {
#pragma unroll
    for (int i = 0; i < 4; ++i) {
      const int row = (tid + i * 512) >> 5;
      rb[i] = *(const bf16x8_t*)(A + (size_t)(row0 + t * RC + row) * DIM + cst * 8);
    }
  };
  auto xform = [&](int b, bf16x8_t* r) {
#pragma unroll
    for (int i = 0; i < 4; ++i) {
      const int row = (tid + i * 512) >> 5;
      bf16x8_t v = r[i];
      bf16x8_t o;
#pragma unroll
      for (int j = 0; j < 8; ++j)
        o[j] = f2bf(fmaxf(fmaf(bf2f(v[j]), sc0[j], sh0[j]), 0.0f));
      *(bf16x8_t*)(&As[b][row * DIM + ((cst ^ (row & 7)) << 3)]) = o;
    }
  };

  auto compute = [&](int t, int b) {
    const f32x4_t zero = {0.f, 0.f, 0.f, 0.f};
    f32x4_t acc[4][2];
#pragma unroll
    for (int m = 0; m < 4; ++m) { acc[m][0] = zero; acc[m][1] = zero; }
    const short* base = As[b];
#pragma unroll
    for (int ks = 0; ks < 8; ++ks) {
      bf16x8_t af[4];
#pragma unroll
      for (int m = 0; m < 4; ++m) {
        const int row = m * 16 + rl;
        const int c = ks * 4 + kh;
        af[m] = *(const bf16x8_t*)(base + row * DIM + ((c ^ (row & 7)) << 3));
      }
#pragma unroll
      for (int m = 0; m < 4; ++m) {
        acc[m][0] = __builtin_amdgcn_mfma_f32_16x16x32_bf16(af[m], wf[0][ks], acc[m][0], 0, 0, 0);
        acc[m][1] = __builtin_amdgcn_mfma_f32_16x16x32_bf16(af[m], wf[1][ks], acc[m][1], 0, 0, 0);
      }
    }
    const int rquad = kh << 2;
#pragma unroll
    for (int n = 0; n < 2; ++n) {
      const int col = colbase + n * 16 + rl;
      float s = 0.f, q = 0.f;
#pragma unroll
      for (int m = 0; m < 4; ++m) {
        const size_t rb2 = (size_t)(row0 + t * RC + m * 16 + rquad) * DIM + col;
#pragma unroll
        for (int r = 0; r < 4; ++r) {
          const float f = acc[m][n][r];
          C[rb2 + (size_t)r * DIM] = f2bf(f);
          s += f;
          q = fmaf(f, f, q);
        }
      }
      if (n == 0) { st_s0 += s; st_q0 += q; }
      else        { st_s1 += s; st_q1 += q; }
    }
  };

  ldregA(0);
  xform(0, ra);
  ldregB(1);
  __syncthreads();
  for (int t = 0; t < NCH; t += 2) {
    if (t + 2 < NCH) ldregA(t + 2);
    compute(t, 0);
    xform(1, rb);
    __syncthreads();
    if (t + 3 < NCH) ldregB(t + 3);
    compute(t + 1, 1);
    if (t + 2 < NCH) xform(0, ra);
    __syncthreads();
  }

  {
    float s = st_s0, q = st_q0;
    s += __shfl_xor(s, 16); s += __shfl_xor(s, 32);
    q += __shfl_xor(q, 16); q += __shfl_xor(q, 32);
    if (lane < 16) {
      psum[(size_t)blockIdx.x * DIM + colbase + rl] = s;
      psq [(size_t)blockIdx.x * DIM + colbase + rl] = q;
    }
  }
  {
    float s = st_s1, q = st_q1;
    s += __shfl_xor(s, 16); s += __shfl_xor(s, 32);
    q += __shfl_xor(q, 16); q += __shfl_xor(q, 32);
    if (lane < 16) {
      psum[(size_t)blockIdx.x * DIM + colbase + 16 + rl] = s;
      psq [(size_t)blockIdx.x * DIM + colbase + 16 + rl] = q;
    }
  }
}

// ---------------- Kernel 3: finalize batch stats -> scale/shift --------------
extern "C" __global__ void __launch_bounds__(64)
k_stats(const float* __restrict__ psum, const float* __restrict__ psq,
        const float* __restrict__ gamma, const float* __restrict__ beta,
        float* __restrict__ sc, float* __restrict__ sh, int nblk) {
  const int c = blockIdx.x;
  const int lane = threadIdx.x;
  float s = 0.0f, q = 0.0f;
  for (int b = lane; b < nblk; b += 64) {
    s += psum[(size_t)b * DIM + c];
    q += psq[(size_t)b * DIM + c];
  }
#pragma unroll
  for (int off = 32; off >= 1; off >>= 1) {
    s += __shfl_xor(s, off);
    q += __shfl_xor(q, off);
  }
  if (lane == 0) {
    const float inv = 1.0f / NEDGE;
    const float mu = s * inv;
    const float var = q * inv - mu * mu;
    const float scale = rsqrtf(var + EPSV) * gamma[c];
    sc[c] = scale;
    sh[c] = beta[c] - mu * scale;
  }
}

// ---------------- Kernel 4: logits = relu(bn3(h3)) . w_out ------------------
extern "C" __global__ void __launch_bounds__(256)
k_head(const short* __restrict__ h3, const float* __restrict__ sc,
       const float* __restrict__ sh, const float* __restrict__ wout,
       float* __restrict__ out) {
  const int e = (blockIdx.x << 3) + (threadIdx.x >> 5);
  const int g = threadIdx.x & 31;
  const int c = g * 8;
  const bf16x8_t v = *(const bf16x8_t*)(h3 + (size_t)e * DIM + c);
  float acc = 0.f;
#pragma unroll
  for (int j = 0; j < 8; ++j)
    acc += fmaxf(fmaf(bf2f(v[j]), sc[c + j], sh[c + j]), 0.0f) * wout[c + j];
#pragma unroll
  for (int off = 16; off >= 1; off >>= 1) acc += __shfl_xor(acc, off);
  if (g == 0) out[e] = acc;
}

extern "C" void kernel_launch(void* const* d_in, const int* in_sizes, int n_in,
                              void* d_out, int out_size, void* d_ws, size_t ws_size,
                              hipStream_t stream) {
  const float* x = (const float*)d_in[0];
  const int* ei = (const int*)d_in[1];
  const float* lnw = (const float*)d_in[2];
  const float* Ws = (const float*)d_in[3];
  const float* gammas = (const float*)d_in[4];
  const float* betas = (const float*)d_in[5];
  const float* wout = (const float*)d_in[6];
  float* out = (float*)d_out;

  // Workspace (~158 MB): h 128MB | xb 25.6MB | Wb(L2,L3) 256KB | Wp(L1 swz)
  //                      128KB | psum 2MB | psq 2MB | bn 6KB
  char* ws = (char*)d_ws;
  const size_t HBYTES = (size_t)NEDGE * DIM * 2;
  short* h = (short*)ws;
  short* xb = (short*)(ws + HBYTES);
  short* Wb = (short*)(ws + HBYTES + (size_t)NNODE * DIM * 2);   // layers 2,3
  short* Wp = Wb + (size_t)2 * DIM * DIM;                        // layer 1 swizzled
  char* p = (char*)(Wp + (size_t)DIM * DIM);
  float* psum = (float*)p;
  float* psq = psum + (size_t)G1_BLOCKS * 8 * DIM;
  float* bnsc = psq + (size_t)G1_BLOCKS * 8 * DIM;
  float* bnsh = bnsc + NLAYER * DIM;

  // prep
  k_cvtw<<<DIM, 64, 0, stream>>>(Ws, lnw, Wp);
  k_cvt<<<(2 * DIM * DIM + 255) / 256, 256, 0, stream>>>(
      Ws + (size_t)DIM * DIM, Wb, 2 * DIM * DIM);
  k_cvt_x<<<(NNODE * DIM / 8 + 255) / 256, 256, 0, stream>>>(x, xb, NNODE * DIM / 8);

  // layer 1: barrier-free fused gather+LN+GEMM (W' in LDS)
  k_gemm1f<<<G1_BLOCKS, 512, 0, stream>>>(xb, ei, Wp, h, psum, psq);
  k_stats<<<DIM, 64, 0, stream>>>(psum, psq, gammas, betas, bnsc, bnsh, G1_BLOCKS * 8);

  for (int l = 1; l < NLAYER; ++l) {
    k_gemm_bn<<<GEMM_GRID, 512, 0, stream>>>(h, Wb + (size_t)(l - 1) * DIM * DIM, h,
                                             psum, psq,
                                             bnsc + (size_t)(l - 1) * DIM,
                                             bnsh + (size_t)(l - 1) * DIM);
    k_stats<<<DIM, 64, 0, stream>>>(psum, psq, gammas + (size_t)l * DIM,
                                    betas + (size_t)l * DIM,
                                    bnsc + (size_t)l * DIM, bnsh + (size_t)l * DIM,
                                    GEMM_GRID);
  }
  k_head<<<NEDGE / 8, 256, 0, stream>>>(h, bnsc + (size_t)(NLAYER - 1) * DIM,
                                        bnsh + (size_t)(NLAYER - 1) * DIM, wout, out);
}

// Round 11
// 268.934 us; speedup vs baseline: 1.4053x; 1.4053x over previous
//
#include <hip/hip_runtime.h>
#include <hip/hip_bf16.h>

#define NEDGE 262144
#define DIM 256
#define NNODE 50000
#define NLAYER 3
#define EPSV 1e-5f

#define GBM 512                 // rows per GEMM block
#define RC 64                   // rows per chunk
#define NCH (GBM / RC)          // 8 chunks per block
#define GEMM_GRID (NEDGE / GBM) // 512 blocks

typedef __attribute__((ext_vector_type(8))) short bf16x8_t;
typedef __attribute__((ext_vector_type(4))) short bf16x4_t;
typedef __attribute__((ext_vector_type(4))) float f32x4_t;

__device__ __forceinline__ float bf2f(short s) {
  unsigned u = ((unsigned)(unsigned short)s) << 16;
  return __builtin_bit_cast(float, u);
}
__device__ __forceinline__ short f2bf(float f) {
  __hip_bfloat16 h = __float2bfloat16(f);
  return __builtin_bit_cast(short, h);
}

// ---------------- Kernel 0a: convert Ws (fp32) -> bf16 ----------------
extern "C" __global__ void __launch_bounds__(256)
k_cvt(const float* __restrict__ src, short* __restrict__ dst, int n) {
  int i = blockIdx.x * 256 + threadIdx.x;
  if (i < n) dst[i] = f2bf(src[i]);
}

// ---------------- Kernel 0b: convert x (fp32) -> bf16, 8 elems/thread -------
extern "C" __global__ void __launch_bounds__(256)
k_cvt_x(const float* __restrict__ src, short* __restrict__ dst, int n8) {
  int i = blockIdx.x * 256 + threadIdx.x;
  if (i >= n8) return;
  const float4 a = *(const float4*)(src + (size_t)i * 8);
  const float4 b = *(const float4*)(src + (size_t)i * 8 + 4);
  bf16x8_t o;
  o[0] = f2bf(a.x); o[1] = f2bf(a.y); o[2] = f2bf(a.z); o[3] = f2bf(a.w);
  o[4] = f2bf(b.x); o[5] = f2bf(b.y); o[6] = f2bf(b.z); o[7] = f2bf(b.w);
  *(bf16x8_t*)(dst + (size_t)i * 8) = o;
}

// ======== Kernel 1: FUSED gather+LN+GEMM1:  C = LN(xb[s]+xb[d]) @ W^T ========
// R5-proven structure (sync/staging/gather identical). One delta: MFMA operand
// order swapped -> D[row=W-col quad][col=edge row]; each lane stores 4
// consecutive W-cols of one edge row as ONE 8B store (8 stores/thread vs 32).
extern "C" __global__ void __launch_bounds__(512)
k_gemm1f(const short* __restrict__ xb, const int* __restrict__ ei,
         const float* __restrict__ lnw, const short* __restrict__ W,
         short* __restrict__ C, float* __restrict__ psum, float* __restrict__ psq) {
  __shared__ short As[2][RC * DIM];  // 2 x 32 KB
  __shared__ int sIdx[GBM], dIdx[GBM];
  const int tid = threadIdx.x;
  const int w = tid >> 6;
  const int lane = tid & 63;
  const int rl = lane & 15;
  const int kh = lane >> 4;
  const int row0 = blockIdx.x * GBM;
  const int colbase = w * 32;
  const int cst = tid & 31;

  sIdx[tid] = ei[row0 + tid];
  dIdx[tid] = ei[NEDGE + row0 + tid];

  bf16x8_t wf[2][8];
#pragma unroll
  for (int n = 0; n < 2; ++n)
#pragma unroll
    for (int ks = 0; ks < 8; ++ks)
      wf[n][ks] = *(const bf16x8_t*)(W + (size_t)(colbase + n * 16 + rl) * DIM + ks * 32 + kh * 8);

  float lw[8];
#pragma unroll
  for (int j = 0; j < 8; ++j) lw[j] = lnw[cst * 8 + j];

  // per-lane column stats: cols colbase + n*16 + kh*4 + r
  float st_s[2][4], st_q[2][4];
#pragma unroll
  for (int n = 0; n < 2; ++n)
#pragma unroll
    for (int r = 0; r < 4; ++r) { st_s[n][r] = 0.f; st_q[n][r] = 0.f; }

  // two named staging sets (even chunks -> A, odd -> B); 32 VGPR each
  bf16x8_t rsA[4], rdA[4], rsB[4], rdB[4];

  auto ldgA = [&](int t) {
#pragma unroll
    for (int i = 0; i < 4; ++i) {
      const int r = (tid >> 5) + 16 * i;
      const int s = sIdx[t * RC + r];
      const int d = dIdx[t * RC + r];
      rsA[i] = *(const bf16x8_t*)(xb + (size_t)s * DIM + cst * 8);
      rdA[i] = *(const bf16x8_t*)(xb + (size_t)d * DIM + cst * 8);
    }
  };
  auto ldgB = [&](int t) {
#pragma unroll
    for (int i = 0; i < 4; ++i) {
      const int r = (tid >> 5) + 16 * i;
      const int s = sIdx[t * RC + r];
      const int d = dIdx[t * RC + r];
      rsB[i] = *(const bf16x8_t*)(xb + (size_t)s * DIM + cst * 8);
      rdB[i] = *(const bf16x8_t*)(xb + (size_t)d * DIM + cst * 8);
    }
  };

  auto lnwr = [&](int b, bf16x8_t* rs, bf16x8_t* rd) {
#pragma unroll
    for (int i = 0; i < 4; ++i) {
      const int r = (tid >> 5) + 16 * i;
      float v[8];
#pragma unroll
      for (int j = 0; j < 8; ++j) v[j] = bf2f(rs[i][j]) + bf2f(rd[i][j]);
      float s = 0.f, ss = 0.f;
#pragma unroll
      for (int j = 0; j < 8; ++j) { s += v[j]; ss = fmaf(v[j], v[j], ss); }
#pragma unroll
      for (int off = 16; off >= 1; off >>= 1) {
        s += __shfl_xor(s, off);
        ss += __shfl_xor(ss, off);
      }
      const float mu = s * (1.0f / DIM);
      const float var = ss * (1.0f / DIM) - mu * mu;
      const float sc = rsqrtf(var + EPSV);
      bf16x8_t o;
#pragma unroll
      for (int j = 0; j < 8; ++j) o[j] = f2bf((v[j] - mu) * sc * lw[j]);
      *(bf16x8_t*)(&As[b][r * DIM + ((cst ^ (r & 7)) << 3)]) = o;
    }
  };

  auto compute = [&](int t, int b) {
    const f32x4_t zero = {0.f, 0.f, 0.f, 0.f};
    f32x4_t acc[4][2];
#pragma unroll
    for (int m = 0; m < 4; ++m) { acc[m][0] = zero; acc[m][1] = zero; }
    const short* base = As[b];
#pragma unroll
    for (int ks = 0; ks < 8; ++ks) {
      bf16x8_t af[4];
#pragma unroll
      for (int m = 0; m < 4; ++m) {
        const int row = m * 16 + rl;
        const int c = ks * 4 + kh;
        af[m] = *(const bf16x8_t*)(base + row * DIM + ((c ^ (row & 7)) << 3));
      }
      // swapped operands: D[row = W-col][col = edge row]
#pragma unroll
      for (int m = 0; m < 4; ++m) {
        acc[m][0] = __builtin_amdgcn_mfma_f32_16x16x32_bf16(wf[0][ks], af[m], acc[m][0], 0, 0, 0);
        acc[m][1] = __builtin_amdgcn_mfma_f32_16x16x32_bf16(wf[1][ks], af[m], acc[m][1], 0, 0, 0);
      }
    }
    // epilogue: lane holds W-cols colbase+n*16+kh*4+r for edge row m*16+rl
    //  -> one 8B store per (m,n); stats accumulate per-lane, reduced at end.
#pragma unroll
    for (int m = 0; m < 4; ++m) {
      const size_t grow = (size_t)(row0 + t * RC + m * 16 + rl) * DIM;
#pragma unroll
      for (int n = 0; n < 2; ++n) {
        bf16x4_t o;
#pragma unroll
        for (int r = 0; r < 4; ++r) {
          const float f = acc[m][n][r];
          o[r] = f2bf(f);
          st_s[n][r] += f;
          st_q[n][r] = fmaf(f, f, st_q[n][r]);
        }
        *(bf16x4_t*)(C + grow + colbase + n * 16 + (kh << 2)) = o;
      }
    }
  };

  __syncthreads();    // idx arrays ready
  ldgA(0);            // chunk 0 -> set A
  ldgB(1);            // chunk 1 -> set B
  lnwr(0, rsA, rdA);  // counted vmcnt: waits set A only
  __syncthreads();
  for (int t = 0; t < NCH; t += 2) {
    if (t + 2 < NCH) ldgA(t + 2);        // issue ahead; flies over compute
    compute(t, 0);
    lnwr(1, rsB, rdB);                   // chunk t+1 -> buf1
    __syncthreads();
    if (t + 3 < NCH) ldgB(t + 3);
    compute(t + 1, 1);
    if (t + 2 < NCH) lnwr(0, rsA, rdA);  // chunk t+2 -> buf0
    __syncthreads();
  }

  // block column stats: reduce over the 16 rl-lanes of each kh group
#pragma unroll
  for (int n = 0; n < 2; ++n)
#pragma unroll
    for (int r = 0; r < 4; ++r) {
      float s = st_s[n][r], q = st_q[n][r];
      s += __shfl_xor(s, 1); s += __shfl_xor(s, 2);
      s += __shfl_xor(s, 4); s += __shfl_xor(s, 8);
      q += __shfl_xor(q, 1); q += __shfl_xor(q, 2);
      q += __shfl_xor(q, 4); q += __shfl_xor(q, 8);
      if (rl == 0) {
        const int col = colbase + n * 16 + (kh << 2) + r;
        psum[(size_t)blockIdx.x * DIM + col] = s;
        psq [(size_t)blockIdx.x * DIM + col] = q;
      }
    }
}

// -------- Kernel 2: BN-layer GEMM (R5-proven, exact): C = relu(A*sc+sh)@W^T --
extern "C" __global__ void __launch_bounds__(512, 2)
k_gemm_bn(const short* __restrict__ A, const short* __restrict__ W,
          short* __restrict__ C, float* __restrict__ psum, float* __restrict__ psq,
          const float* __restrict__ bsc, const float* __restrict__ bsh) {
  __shared__ short As[2][RC * DIM];
  const int tid = threadIdx.x;
  const int w = tid >> 6;
  const int lane = tid & 63;
  const int rl = lane & 15;
  const int kh = lane >> 4;
  const int row0 = blockIdx.x * GBM;
  const int colbase = w * 32;

  bf16x8_t wf[2][8];
#pragma unroll
  for (int n = 0; n < 2; ++n)
#pragma unroll
    for (int ks = 0; ks < 8; ++ks)
      wf[n][ks] = *(const bf16x8_t*)(W + (size_t)(colbase + n * 16 + rl) * DIM + ks * 32 + kh * 8);

  const int cst = tid & 31;
  float sc0[8], sh0[8];
#pragma unroll
  for (int j = 0; j < 8; ++j) {
    sc0[j] = bsc[cst * 8 + j];
    sh0[j] = bsh[cst * 8 + j];
  }

  float st_s0 = 0.f, st_s1 = 0.f, st_q0 = 0.f, st_q1 = 0.f;

  bf16x8_t ra[4], rb[4];
  auto ldregA = [&](int t) {
#pragma unroll
    for (int i = 0; i < 4; ++i) {
      const int row = (tid + i * 512) >> 5;
      ra[i] = *(const bf16x8_t*)(A + (size_t)(row0 + t * RC + row) * DIM + cst * 8);
    }
  };
  auto ldregB = [&](int t) {
#pragma unroll
    for (int i = 0; i < 4; ++i) {
      const int row = (tid + i * 512) >> 5;
      rb[i] = *(const bf16x8_t*)(A + (size_t)(row0 + t * RC + row) * DIM + cst * 8);
    }
  };
  auto xform = [&](int b, bf16x8_t* r) {
#pragma unroll
    for (int i = 0; i < 4; ++i) {
      const int row = (tid + i * 512) >> 5;
      bf16x8_t v = r[i];
      bf16x8_t o;
#pragma unroll
      for (int j = 0; j < 8; ++j)
        o[j] = f2bf(fmaxf(fmaf(bf2f(v[j]), sc0[j], sh0[j]), 0.0f));
      *(bf16x8_t*)(&As[b][row * DIM + ((cst ^ (row & 7)) << 3)]) = o;
    }
  };

  auto compute = [&](int t, int b) {
    const f32x4_t zero = {0.f, 0.f, 0.f, 0.f};
    f32x4_t acc[4][2];
#pragma unroll
    for (int m = 0; m < 4; ++m) { acc[m][0] = zero; acc[m][1] = zero; }
    const short* base = As[b];
#pragma unroll
    for (int ks = 0; ks < 8; ++ks) {
      bf16x8_t af[4];
#pragma unroll
      for (int m = 0; m < 4; ++m) {
        const int row = m * 16 + rl;
        const int c = ks * 4 + kh;
        af[m] = *(const bf16x8_t*)(base + row * DIM + ((c ^ (row & 7)) << 3));
      }
#pragma unroll
      for (int m = 0; m < 4; ++m) {
        acc[m][0] = __builtin_amdgcn_mfma_f32_16x16x32_bf16(af[m], wf[0][ks], acc[m][0], 0, 0, 0);
        acc[m][1] = __builtin_amdgcn_mfma_f32_16x16x32_bf16(af[m], wf[1][ks], acc[m][1], 0, 0, 0);
      }
    }
    const int rquad = kh << 2;
#pragma unroll
    for (int n = 0; n < 2; ++n) {
      const int col = colbase + n * 16 + rl;
      float s = 0.f, q = 0.f;
#pragma unroll
      for (int m = 0; m < 4; ++m) {
        const size_t rb2 = (size_t)(row0 + t * RC + m * 16 + rquad) * DIM + col;
#pragma unroll
        for (int r = 0; r < 4; ++r) {
          const float f = acc[m][n][r];
          C[rb2 + (size_t)r * DIM] = f2bf(f);
          s += f;
          q = fmaf(f, f, q);
        }
      }
      if (n == 0) { st_s0 += s; st_q0 += q; }
      else        { st_s1 += s; st_q1 += q; }
    }
  };

  ldregA(0);
  xform(0, ra);
  ldregB(1);
  __syncthreads();
  for (int t = 0; t < NCH; t += 2) {
    if (t + 2 < NCH) ldregA(t + 2);
    compute(t, 0);
    xform(1, rb);
    __syncthreads();
    if (t + 3 < NCH) ldregB(t + 3);
    compute(t + 1, 1);
    if (t + 2 < NCH) xform(0, ra);
    __syncthreads();
  }

  {
    float s = st_s0, q = st_q0;
    s += __shfl_xor(s, 16); s += __shfl_xor(s, 32);
    q += __shfl_xor(q, 16); q += __shfl_xor(q, 32);
    if (lane < 16) {
      psum[(size_t)blockIdx.x * DIM + colbase + rl] = s;
      psq [(size_t)blockIdx.x * DIM + colbase + rl] = q;
    }
  }
  {
    float s = st_s1, q = st_q1;
    s += __shfl_xor(s, 16); s += __shfl_xor(s, 32);
    q += __shfl_xor(q, 16); q += __shfl_xor(q, 32);
    if (lane < 16) {
      psum[(size_t)blockIdx.x * DIM + colbase + 16 + rl] = s;
      psq [(size_t)blockIdx.x * DIM + colbase + 16 + rl] = q;
    }
  }
}

// ---------------- Kernel 3: finalize batch stats -> scale/shift --------------
extern "C" __global__ void __launch_bounds__(64)
k_stats(const float* __restrict__ psum, const float* __restrict__ psq,
        const float* __restrict__ gamma, const float* __restrict__ beta,
        float* __restrict__ sc, float* __restrict__ sh, int nblk) {
  const int c = blockIdx.x;
  const int lane = threadIdx.x;
  float s = 0.0f, q = 0.0f;
  for (int b = lane; b < nblk; b += 64) {
    s += psum[(size_t)b * DIM + c];
    q += psq[(size_t)b * DIM + c];
  }
#pragma unroll
  for (int off = 32; off >= 1; off >>= 1) {
    s += __shfl_xor(s, off);
    q += __shfl_xor(q, off);
  }
  if (lane == 0) {
    const float inv = 1.0f / NEDGE;
    const float mu = s * inv;
    const float var = q * inv - mu * mu;
    const float scale = rsqrtf(var + EPSV) * gamma[c];
    sc[c] = scale;
    sh[c] = beta[c] - mu * scale;
  }
}

// ---------------- Kernel 4: logits = relu(bn3(h3)) . w_out ------------------
extern "C" __global__ void __launch_bounds__(256)
k_head(const short* __restrict__ h3, const float* __restrict__ sc,
       const float* __restrict__ sh, const float* __restrict__ wout,
       float* __restrict__ out) {
  const int e = (blockIdx.x << 3) + (threadIdx.x >> 5);
  const int g = threadIdx.x & 31;
  const int c = g * 8;
  const bf16x8_t v = *(const bf16x8_t*)(h3 + (size_t)e * DIM + c);
  float acc = 0.f;
#pragma unroll
  for (int j = 0; j < 8; ++j)
    acc += fmaxf(fmaf(bf2f(v[j]), sc[c + j], sh[c + j]), 0.0f) * wout[c + j];
#pragma unroll
  for (int off = 16; off >= 1; off >>= 1) acc += __shfl_xor(acc, off);
  if (g == 0) out[e] = acc;
}

extern "C" void kernel_launch(void* const* d_in, const int* in_sizes, int n_in,
                              void* d_out, int out_size, void* d_ws, size_t ws_size,
                              hipStream_t stream) {
  const float* x = (const float*)d_in[0];
  const int* ei = (const int*)d_in[1];
  const float* lnw = (const float*)d_in[2];
  const float* Ws = (const float*)d_in[3];
  const float* gammas = (const float*)d_in[4];
  const float* betas = (const float*)d_in[5];
  const float* wout = (const float*)d_in[6];
  float* out = (float*)d_out;

  // Workspace (~155 MB): h 128MB | Wb 384KB | psum 512KB | psq 512KB | bn 6KB | xb 25.6MB
  char* ws = (char*)d_ws;
  const size_t HBYTES = (size_t)NEDGE * DIM * 2;
  short* h = (short*)ws;
  short* Wb = (short*)(ws + HBYTES);
  char* p = ws + HBYTES + (size_t)NLAYER * DIM * DIM * 2;
  float* psum = (float*)p;
  float* psq = psum + (size_t)GEMM_GRID * DIM;
  float* bnsc = psq + (size_t)GEMM_GRID * DIM;
  float* bnsh = bnsc + NLAYER * DIM;
  short* xb = (short*)(bnsh + NLAYER * DIM);

  k_cvt<<<(NLAYER * DIM * DIM + 255) / 256, 256, 0, stream>>>(Ws, Wb, NLAYER * DIM * DIM);
  k_cvt_x<<<(NNODE * DIM / 8 + 255) / 256, 256, 0, stream>>>(x, xb, NNODE * DIM / 8);

  // layer 1: fused gather+LN+GEMM
  k_gemm1f<<<GEMM_GRID, 512, 0, stream>>>(xb, ei, lnw, Wb, h, psum, psq);
  k_stats<<<DIM, 64, 0, stream>>>(psum, psq, gammas, betas, bnsc, bnsh, GEMM_GRID);

  for (int l = 1; l < NLAYER; ++l) {
    k_gemm_bn<<<GEMM_GRID, 512, 0, stream>>>(h, Wb + (size_t)l * DIM * DIM, h,
                                             psum, psq,
                                             bnsc + (size_t)(l - 1) * DIM,
                                             bnsh + (size_t)(l - 1) * DIM);
    k_stats<<<DIM, 64, 0, stream>>>(psum, psq, gammas + (size_t)l * DIM,
                                    betas + (size_t)l * DIM,
                                    bnsc + (size_t)l * DIM, bnsh + (size_t)l * DIM,
                                    GEMM_GRID);
  }
  k_head<<<NEDGE / 8, 256, 0, stream>>>(h, bnsc + (size_t)(NLAYER - 1) * DIM,
                                        bnsh + (size_t)(NLAYER - 1) * DIM, wout, out);
}

// Round 12
// 255.721 us; speedup vs baseline: 1.4780x; 1.0517x over previous
//
#include <hip/hip_runtime.h>
#include <hip/hip_bf16.h>

#define NEDGE 262144
#define DIM 256
#define NNODE 50000
#define NLAYER 3
#define EPSV 1e-5f

#define GBM 512                 // rows per GEMM block
#define RC 64                   // rows per chunk
#define NCH (GBM / RC)          // 8 chunks per block
#define GEMM_GRID (NEDGE / GBM) // 512 blocks

typedef __attribute__((ext_vector_type(8))) short bf16x8_t;
typedef __attribute__((ext_vector_type(4))) float f32x4_t;

__device__ __forceinline__ float bf2f(short s) {
  unsigned u = ((unsigned)(unsigned short)s) << 16;
  return __builtin_bit_cast(float, u);
}
__device__ __forceinline__ short f2bf(float f) {
  __hip_bfloat16 h = __float2bfloat16(f);
  return __builtin_bit_cast(short, h);
}

// ---------------- Kernel 0a: convert Ws (fp32) -> bf16 ----------------
extern "C" __global__ void __launch_bounds__(256)
k_cvt(const float* __restrict__ src, short* __restrict__ dst, int n) {
  int i = blockIdx.x * 256 + threadIdx.x;
  if (i < n) dst[i] = f2bf(src[i]);
}

// ---------------- Kernel 0b: convert x (fp32) -> bf16, 8 elems/thread -------
extern "C" __global__ void __launch_bounds__(256)
k_cvt_x(const float* __restrict__ src, short* __restrict__ dst, int n8) {
  int i = blockIdx.x * 256 + threadIdx.x;
  if (i >= n8) return;
  const float4 a = *(const float4*)(src + (size_t)i * 8);
  const float4 b = *(const float4*)(src + (size_t)i * 8 + 4);
  bf16x8_t o;
  o[0] = f2bf(a.x); o[1] = f2bf(a.y); o[2] = f2bf(a.z); o[3] = f2bf(a.w);
  o[4] = f2bf(b.x); o[5] = f2bf(b.y); o[6] = f2bf(b.z); o[7] = f2bf(b.w);
  *(bf16x8_t*)(dst + (size_t)i * 8) = o;
}

// ======== Kernel 1: FUSED gather+LN+GEMM1:  C = LN(xb[s]+xb[d]) @ W^T ========
// R5-verified form. 8 waves x 512 threads; wave w owns cols [w*32,+32), W in
// 64 VGPRs. 2-deep reg-staged gather prefetch; __syncthreads-drained pipeline.
// At the L1-miss-concurrency roofline for the random 2x512B/row gather.
extern "C" __global__ void __launch_bounds__(512)
k_gemm1f(const short* __restrict__ xb, const int* __restrict__ ei,
         const float* __restrict__ lnw, const short* __restrict__ W,
         short* __restrict__ C, float* __restrict__ psum, float* __restrict__ psq) {
  __shared__ short As[2][RC * DIM];  // 2 x 32 KB
  __shared__ int sIdx[GBM], dIdx[GBM];
  const int tid = threadIdx.x;
  const int w = tid >> 6;
  const int lane = tid & 63;
  const int rl = lane & 15;
  const int kh = lane >> 4;
  const int row0 = blockIdx.x * GBM;
  const int colbase = w * 32;
  const int cst = tid & 31;

  sIdx[tid] = ei[row0 + tid];
  dIdx[tid] = ei[NEDGE + row0 + tid];

  bf16x8_t wf[2][8];
#pragma unroll
  for (int n = 0; n < 2; ++n)
#pragma unroll
    for (int ks = 0; ks < 8; ++ks)
      wf[n][ks] = *(const bf16x8_t*)(W + (size_t)(colbase + n * 16 + rl) * DIM + ks * 32 + kh * 8);

  float lw[8];
#pragma unroll
  for (int j = 0; j < 8; ++j) lw[j] = lnw[cst * 8 + j];

  float st_s0 = 0.f, st_s1 = 0.f, st_q0 = 0.f, st_q1 = 0.f;

  // two named staging sets (even chunks -> A, odd -> B); 32 VGPR each
  bf16x8_t rsA[4], rdA[4], rsB[4], rdB[4];

  auto ldgA = [&](int t) {
#pragma unroll
    for (int i = 0; i < 4; ++i) {
      const int r = (tid >> 5) + 16 * i;
      const int s = sIdx[t * RC + r];
      const int d = dIdx[t * RC + r];
      rsA[i] = *(const bf16x8_t*)(xb + (size_t)s * DIM + cst * 8);
      rdA[i] = *(const bf16x8_t*)(xb + (size_t)d * DIM + cst * 8);
    }
  };
  auto ldgB = [&](int t) {
#pragma unroll
    for (int i = 0; i < 4; ++i) {
      const int r = (tid >> 5) + 16 * i;
      const int s = sIdx[t * RC + r];
      const int d = dIdx[t * RC + r];
      rsB[i] = *(const bf16x8_t*)(xb + (size_t)s * DIM + cst * 8);
      rdB[i] = *(const bf16x8_t*)(xb + (size_t)d * DIM + cst * 8);
    }
  };

  auto lnwr = [&](int b, bf16x8_t* rs, bf16x8_t* rd) {
#pragma unroll
    for (int i = 0; i < 4; ++i) {
      const int r = (tid >> 5) + 16 * i;
      float v[8];
#pragma unroll
      for (int j = 0; j < 8; ++j) v[j] = bf2f(rs[i][j]) + bf2f(rd[i][j]);
      float s = 0.f, ss = 0.f;
#pragma unroll
      for (int j = 0; j < 8; ++j) { s += v[j]; ss = fmaf(v[j], v[j], ss); }
#pragma unroll
      for (int off = 16; off >= 1; off >>= 1) {
        s += __shfl_xor(s, off);
        ss += __shfl_xor(ss, off);
      }
      const float mu = s * (1.0f / DIM);
      const float var = ss * (1.0f / DIM) - mu * mu;
      const float sc = rsqrtf(var + EPSV);
      bf16x8_t o;
#pragma unroll
      for (int j = 0; j < 8; ++j) o[j] = f2bf((v[j] - mu) * sc * lw[j]);
      *(bf16x8_t*)(&As[b][r * DIM + ((cst ^ (r & 7)) << 3)]) = o;
    }
  };

  auto compute = [&](int t, int b) {
    const f32x4_t zero = {0.f, 0.f, 0.f, 0.f};
    f32x4_t acc[4][2];
#pragma unroll
    for (int m = 0; m < 4; ++m) { acc[m][0] = zero; acc[m][1] = zero; }
    const short* base = As[b];
#pragma unroll
    for (int ks = 0; ks < 8; ++ks) {
      bf16x8_t af[4];
#pragma unroll
      for (int m = 0; m < 4; ++m) {
        const int row = m * 16 + rl;
        const int c = ks * 4 + kh;
        af[m] = *(const bf16x8_t*)(base + row * DIM + ((c ^ (row & 7)) << 3));
      }
#pragma unroll
      for (int m = 0; m < 4; ++m) {
        acc[m][0] = __builtin_amdgcn_mfma_f32_16x16x32_bf16(af[m], wf[0][ks], acc[m][0], 0, 0, 0);
        acc[m][1] = __builtin_amdgcn_mfma_f32_16x16x32_bf16(af[m], wf[1][ks], acc[m][1], 0, 0, 0);
      }
    }
    const int rquad = kh << 2;
#pragma unroll
    for (int n = 0; n < 2; ++n) {
      const int col = colbase + n * 16 + rl;
      float s = 0.f, q = 0.f;
#pragma unroll
      for (int m = 0; m < 4; ++m) {
        const size_t rb = (size_t)(row0 + t * RC + m * 16 + rquad) * DIM + col;
#pragma unroll
        for (int r = 0; r < 4; ++r) {
          const float f = acc[m][n][r];
          C[rb + (size_t)r * DIM] = f2bf(f);
          s += f;
          q = fmaf(f, f, q);
        }
      }
      if (n == 0) { st_s0 += s; st_q0 += q; }
      else        { st_s1 += s; st_q1 += q; }
    }
  };

  __syncthreads();    // idx arrays ready
  ldgA(0);            // chunk 0 -> set A
  ldgB(1);            // chunk 1 -> set B
  lnwr(0, rsA, rdA);  // counted vmcnt: waits set A only
  __syncthreads();
  for (int t = 0; t < NCH; t += 2) {
    if (t + 2 < NCH) ldgA(t + 2);        // issue ahead; flies over compute
    compute(t, 0);
    lnwr(1, rsB, rdB);                   // chunk t+1 -> buf1
    __syncthreads();
    if (t + 3 < NCH) ldgB(t + 3);
    compute(t + 1, 1);
    if (t + 2 < NCH) lnwr(0, rsA, rdA);  // chunk t+2 -> buf0
    __syncthreads();
  }

  {
    float s = st_s0, q = st_q0;
    s += __shfl_xor(s, 16); s += __shfl_xor(s, 32);
    q += __shfl_xor(q, 16); q += __shfl_xor(q, 32);
    if (lane < 16) {
      psum[(size_t)blockIdx.x * DIM + colbase + rl] = s;
      psq [(size_t)blockIdx.x * DIM + colbase + rl] = q;
    }
  }
  {
    float s = st_s1, q = st_q1;
    s += __shfl_xor(s, 16); s += __shfl_xor(s, 32);
    q += __shfl_xor(q, 16); q += __shfl_xor(q, 32);
    if (lane < 16) {
      psum[(size_t)blockIdx.x * DIM + colbase + 16 + rl] = s;
      psq [(size_t)blockIdx.x * DIM + colbase + 16 + rl] = q;
    }
  }
}

// -------- Kernel 2: BN-layer GEMM (R5-proven, exact): C = relu(A*sc+sh)@W^T --
extern "C" __global__ void __launch_bounds__(512, 2)
k_gemm_bn(const short* __restrict__ A, const short* __restrict__ W,
          short* __restrict__ C, float* __restrict__ psum, float* __restrict__ psq,
          const float* __restrict__ bsc, const float* __restrict__ bsh) {
  __shared__ short As[2][RC * DIM];
  const int tid = threadIdx.x;
  const int w = tid >> 6;
  const int lane = tid & 63;
  const int rl = lane & 15;
  const int kh = lane >> 4;
  const int row0 = blockIdx.x * GBM;
  const int colbase = w * 32;

  bf16x8_t wf[2][8];
#pragma unroll
  for (int n = 0; n < 2; ++n)
#pragma unroll
    for (int ks = 0; ks < 8; ++ks)
      wf[n][ks] = *(const bf16x8_t*)(W + (size_t)(colbase + n * 16 + rl) * DIM + ks * 32 + kh * 8);

  const int cst = tid & 31;
  float sc0[8], sh0[8];
#pragma unroll
  for (int j = 0; j < 8; ++j) {
    sc0[j] = bsc[cst * 8 + j];
    sh0[j] = bsh[cst * 8 + j];
  }

  float st_s0 = 0.f, st_s1 = 0.f, st_q0 = 0.f, st_q1 = 0.f;

  bf16x8_t ra[4], rb[4];
  auto ldregA = [&](int t) {
#pragma unroll
    for (int i = 0; i < 4; ++i) {
      const int row = (tid + i * 512) >> 5;
      ra[i] = *(const bf16x8_t*)(A + (size_t)(row0 + t * RC + row) * DIM + cst * 8);
    }
  };
  auto ldregB = [&](int t) {
#pragma unroll
    for (int i = 0; i < 4; ++i) {
      const int row = (tid + i * 512) >> 5;
      rb[i] = *(const bf16x8_t*)(A + (size_t)(row0 + t * RC + row) * DIM + cst * 8);
    }
  };
  auto xform = [&](int b, bf16x8_t* r) {
#pragma unroll
    for (int i = 0; i < 4; ++i) {
      const int row = (tid + i * 512) >> 5;
      bf16x8_t v = r[i];
      bf16x8_t o;
#pragma unroll
      for (int j = 0; j < 8; ++j)
        o[j] = f2bf(fmaxf(fmaf(bf2f(v[j]), sc0[j], sh0[j]), 0.0f));
      *(bf16x8_t*)(&As[b][row * DIM + ((cst ^ (row & 7)) << 3)]) = o;
    }
  };

  auto compute = [&](int t, int b) {
    const f32x4_t zero = {0.f, 0.f, 0.f, 0.f};
    f32x4_t acc[4][2];
#pragma unroll
    for (int m = 0; m < 4; ++m) { acc[m][0] = zero; acc[m][1] = zero; }
    const short* base = As[b];
#pragma unroll
    for (int ks = 0; ks < 8; ++ks) {
      bf16x8_t af[4];
#pragma unroll
      for (int m = 0; m < 4; ++m) {
        const int row = m * 16 + rl;
        const int c = ks * 4 + kh;
        af[m] = *(const bf16x8_t*)(base + row * DIM + ((c ^ (row & 7)) << 3));
      }
#pragma unroll
      for (int m = 0; m < 4; ++m) {
        acc[m][0] = __builtin_amdgcn_mfma_f32_16x16x32_bf16(af[m], wf[0][ks], acc[m][0], 0, 0, 0);
        acc[m][1] = __builtin_amdgcn_mfma_f32_16x16x32_bf16(af[m], wf[1][ks], acc[m][1], 0, 0, 0);
      }
    }
    const int rquad = kh << 2;
#pragma unroll
    for (int n = 0; n < 2; ++n) {
      const int col = colbase + n * 16 + rl;
      float s = 0.f, q = 0.f;
#pragma unroll
      for (int m = 0; m < 4; ++m) {
        const size_t rb2 = (size_t)(row0 + t * RC + m * 16 + rquad) * DIM + col;
#pragma unroll
        for (int r = 0; r < 4; ++r) {
          const float f = acc[m][n][r];
          C[rb2 + (size_t)r * DIM] = f2bf(f);
          s += f;
          q = fmaf(f, f, q);
        }
      }
      if (n == 0) { st_s0 += s; st_q0 += q; }
      else        { st_s1 += s; st_q1 += q; }
    }
  };

  ldregA(0);
  xform(0, ra);
  ldregB(1);
  __syncthreads();
  for (int t = 0; t < NCH; t += 2) {
    if (t + 2 < NCH) ldregA(t + 2);
    compute(t, 0);
    xform(1, rb);
    __syncthreads();
    if (t + 3 < NCH) ldregB(t + 3);
    compute(t + 1, 1);
    if (t + 2 < NCH) xform(0, ra);
    __syncthreads();
  }

  {
    float s = st_s0, q = st_q0;
    s += __shfl_xor(s, 16); s += __shfl_xor(s, 32);
    q += __shfl_xor(q, 16); q += __shfl_xor(q, 32);
    if (lane < 16) {
      psum[(size_t)blockIdx.x * DIM + colbase + rl] = s;
      psq [(size_t)blockIdx.x * DIM + colbase + rl] = q;
    }
  }
  {
    float s = st_s1, q = st_q1;
    s += __shfl_xor(s, 16); s += __shfl_xor(s, 32);
    q += __shfl_xor(q, 16); q += __shfl_xor(q, 32);
    if (lane < 16) {
      psum[(size_t)blockIdx.x * DIM + colbase + 16 + rl] = s;
      psq [(size_t)blockIdx.x * DIM + colbase + 16 + rl] = q;
    }
  }
}

// ---------------- Kernel 3: finalize batch stats -> scale/shift --------------
extern "C" __global__ void __launch_bounds__(64)
k_stats(const float* __restrict__ psum, const float* __restrict__ psq,
        const float* __restrict__ gamma, const float* __restrict__ beta,
        float* __restrict__ sc, float* __restrict__ sh, int nblk) {
  const int c = blockIdx.x;
  const int lane = threadIdx.x;
  float s = 0.0f, q = 0.0f;
  for (int b = lane; b < nblk; b += 64) {
    s += psum[(size_t)b * DIM + c];
    q += psq[(size_t)b * DIM + c];
  }
#pragma unroll
  for (int off = 32; off >= 1; off >>= 1) {
    s += __shfl_xor(s, off);
    q += __shfl_xor(q, off);
  }
  if (lane == 0) {
    const float inv = 1.0f / NEDGE;
    const float mu = s * inv;
    const float var = q * inv - mu * mu;
    const float scale = rsqrtf(var + EPSV) * gamma[c];
    sc[c] = scale;
    sh[c] = beta[c] - mu * scale;
  }
}

// ---------------- Kernel 4: logits = relu(bn3(h3)) . w_out ------------------
extern "C" __global__ void __launch_bounds__(256)
k_head(const short* __restrict__ h3, const float* __restrict__ sc,
       const float* __restrict__ sh, const float* __restrict__ wout,
       float* __restrict__ out) {
  const int e = (blockIdx.x << 3) + (threadIdx.x >> 5);
  const int g = threadIdx.x & 31;
  const int c = g * 8;
  const bf16x8_t v = *(const bf16x8_t*)(h3 + (size_t)e * DIM + c);
  float acc = 0.f;
#pragma unroll
  for (int j = 0; j < 8; ++j)
    acc += fmaxf(fmaf(bf2f(v[j]), sc[c + j], sh[c + j]), 0.0f) * wout[c + j];
#pragma unroll
  for (int off = 16; off >= 1; off >>= 1) acc += __shfl_xor(acc, off);
  if (g == 0) out[e] = acc;
}

extern "C" void kernel_launch(void* const* d_in, const int* in_sizes, int n_in,
                              void* d_out, int out_size, void* d_ws, size_t ws_size,
                              hipStream_t stream) {
  const float* x = (const float*)d_in[0];
  const int* ei = (const int*)d_in[1];
  const float* lnw = (const float*)d_in[2];
  const float* Ws = (const float*)d_in[3];
  const float* gammas = (const float*)d_in[4];
  const float* betas = (const float*)d_in[5];
  const float* wout = (const float*)d_in[6];
  float* out = (float*)d_out;

  // Workspace (~155 MB): h 128MB | Wb 384KB | psum 512KB | psq 512KB | bn 6KB | xb 25.6MB
  char* ws = (char*)d_ws;
  const size_t HBYTES = (size_t)NEDGE * DIM * 2;
  short* h = (short*)ws;
  short* Wb = (short*)(ws + HBYTES);
  char* p = ws + HBYTES + (size_t)NLAYER * DIM * DIM * 2;
  float* psum = (float*)p;
  float* psq = psum + (size_t)GEMM_GRID * DIM;
  float* bnsc = psq + (size_t)GEMM_GRID * DIM;
  float* bnsh = bnsc + NLAYER * DIM;
  short* xb = (short*)(bnsh + NLAYER * DIM);

  k_cvt<<<(NLAYER * DIM * DIM + 255) / 256, 256, 0, stream>>>(Ws, Wb, NLAYER * DIM * DIM);
  k_cvt_x<<<(NNODE * DIM / 8 + 255) / 256, 256, 0, stream>>>(x, xb, NNODE * DIM / 8);

  // layer 1: fused gather+LN+GEMM
  k_gemm1f<<<GEMM_GRID, 512, 0, stream>>>(xb, ei, lnw, Wb, h, psum, psq);
  k_stats<<<DIM, 64, 0, stream>>>(psum, psq, gammas, betas, bnsc, bnsh, GEMM_GRID);

  for (int l = 1; l < NLAYER; ++l) {
    k_gemm_bn<<<GEMM_GRID, 512, 0, stream>>>(h, Wb + (size_t)l * DIM * DIM, h,
                                             psum, psq,
                                             bnsc + (size_t)(l - 1) * DIM,
                                             bnsh + (size_t)(l - 1) * DIM);
    k_stats<<<DIM, 64, 0, stream>>>(psum, psq, gammas + (size_t)l * DIM,
                                    betas + (size_t)l * DIM,
                                    bnsc + (size_t)l * DIM, bnsh + (size_t)l * DIM,
                                    GEMM_GRID);
  }
  k_head<<<NEDGE / 8, 256, 0, stream>>>(h, bnsc + (size_t)(NLAYER - 1) * DIM,
                                        bnsh + (size_t)(NLAYER - 1) * DIM, wout, out);
}